// Round 12
// baseline (227.031 us; speedup 1.0000x reference)
//
#include <hip/hip_runtime.h>
#include <hip/hip_fp16.h>
#include <stdint.h>

// SoftmaxSelfAttention: B=2 H=16 S=2048 D=64, fp32 in/out.
// R16: R15's no-LDS free-drift body at 4 waves/SIMD. R15 post-mortem: the
// regression (74us) tracked occupancy (18% = 2 waves/SIMD; 512-block grid x
// 256 thr = 2 blocks/CU), not the drift structure itself — VGPR 96, zero
// spill, conflicts 0. Ledger: every 57us point has 4/SIMD; every regression
// has 2/SIMD or spill. The untested cell: free drift AT 4/SIMD.
// Change: kv-halved waves -> grid 1024 (32 qblocks of 64 rows x 32 bh),
// block = 4 waves = qsub(2) x kvhalf(2), each wave sweeps 16 of 32 kv-tiles
// with R15's exact register-resident K-dbuf/V/mi direct-L2 loads. 16
// waves/CU, no barriers in the loop. Epilogue: kvh=1 waves write partials
// to LDS (R11's stride-36 exchange), one __syncthreads, kvh=0 combines.
// launch_bounds(256,4) hard-caps VGPR 128 (body needs ~96) to guarantee
// 4 blocks/CU co-residency (3/CU on a 1024 grid = 2-round tail).

#define S_LEN   2048
#define DHEAD   64
#define CEXP    9.0f
#define SCL2E   0.18033688011112042f    // (1/sqrt(64)) * log2(e)
#define L2E     1.4426950408889634f

typedef __attribute__((ext_vector_type(4))) float    f32x4;
typedef __attribute__((ext_vector_type(2))) _Float16 f16x2;
typedef __attribute__((ext_vector_type(4))) _Float16 f16x4;
typedef __attribute__((ext_vector_type(8))) _Float16 f16x8;
typedef __attribute__((ext_vector_type(2))) __fp16   hf16x2;

static __device__ __forceinline__ float exp2_fast(float x) {
#if __has_builtin(__builtin_amdgcn_exp2f)
  return __builtin_amdgcn_exp2f(x);
#else
  float r;
  asm("v_exp_f32 %0, %1" : "=v"(r) : "v"(x));
  return r;
#endif
}

static __device__ __forceinline__ hf16x2 pkh(float a, float b) {
  return __builtin_amdgcn_cvt_pkrtz(a, b);
}
static __device__ __forceinline__ f16x2 h2f(hf16x2 h) {
  union { hf16x2 i; f16x2 o; } u; u.i = h; return u.o;
}

// ---------------------------------------------------------------- prep ----
// (unchanged from R15, which passed)
// Blocks [0,2048): K image, CHUNK-MAJOR for direct-reg fragment loads:
// dst granule idx = bh<<14 | p<<9 | t<<7 | c<<4 | x holds
// K[bh][kv = p*64+t*16+x][d = c*8 .. +8] as 8 f16. Also madd_g[b][kv].
// Blocks [2048,6144): V image, granule-major:
// granule (bh,j,g,d) = {V[64j+4g+i][d], i=0..3} at flat (bh<<15|j<<10|g<<6|d).
__global__ __launch_bounds__(256) void prep(
    const float* __restrict__ K, const float* __restrict__ V,
    const float* __restrict__ Mk, _Float16* __restrict__ K2,
    _Float16* __restrict__ Vg, float* __restrict__ madd_g) {
  const int gb = blockIdx.x;
  if (gb < 2048) {
    const int idx = gb * 256 + threadIdx.x;   // bh<<14 | p<<9 | t<<7 | c<<4 | x
    const int x  = idx & 15;
    const int c  = (idx >> 4) & 7;
    const int t  = (idx >> 7) & 3;
    const int p  = (idx >> 9) & 31;
    const int bh = idx >> 14;
    const int kv = p * 64 + t * 16 + x;
    const float* src = K + ((size_t)bh * S_LEN + kv) * DHEAD + c * 8;
    float4 a = *(const float4*)(src);
    float4 d = *(const float4*)(src + 4);
    union { f16x2 h[4]; f16x8 v; } r;
    r.h[0] = h2f(pkh(a.x, a.y)); r.h[1] = h2f(pkh(a.z, a.w));
    r.h[2] = h2f(pkh(d.x, d.y)); r.h[3] = h2f(pkh(d.z, d.w));
    *(f16x8*)(K2 + (size_t)idx * 8) = r.v;
    if (idx < 2 * S_LEN)
      madd_g[idx] = -CEXP - (1.0e6f * L2E) * (1.0f - Mk[idx]);
  } else {
    const int idx = (gb - 2048) * 256 + threadIdx.x;  // bh<<15 | j<<10 | g<<6 | d
    const int d  = idx & 63;
    const int g  = (idx >> 6) & 15;
    const int j  = (idx >> 10) & 31;
    const int bh = idx >> 15;
    const float* src = V + ((size_t)bh * S_LEN + j * 64 + g * 4) * DHEAD + d;
    float v0 = src[0], v1 = src[64], v2 = src[128], v3 = src[192];
    union { f16x2 h[2]; f16x4 v; } r;
    r.h[0] = h2f(pkh(v0, v1)); r.h[1] = h2f(pkh(v2, v3));
    *(f16x4*)(Vg + (size_t)idx * 4) = r.v;
  }
}

// ---------------------------------------------------------------- main ----
// 256 threads = 4 free-drifting waves: wave = qsub | kvh<<1.
// Wave (qsub,kvh): q-strips qblk*64 + qsub*32 + {0,16}, kv half kvh.
// No LDS/barriers in the loop; K dbuf in regs, V+mi direct from L2.
// One __syncthreads for the kv-half combine epilogue.
__global__ __launch_bounds__(256, 4) void attn_ws(
    const float* __restrict__ Q, const _Float16* __restrict__ K2,
    const _Float16* __restrict__ Vg, const float* __restrict__ madd_g,
    float* __restrict__ O) {
  __shared__ __align__(16) float xls[4608];   // 18.4KB combine scratch

  const int tid  = threadIdx.x;       // 0..255
  const int lane = tid & 63;
  const int wave = tid >> 6;          // 0..3
  const int qsub = wave & 1;
  const int kvh  = wave >> 1;
  const int quad = lane >> 4;
  const int x    = lane & 15;

  // grid 1024: 32 q-blocks (64 rows) x 32 bh; same-bh blocks share an XCD.
  const int blk  = blockIdx.x;
  const int bh   = (blk & 7) | (((blk >> 3) & 3) << 3);
  const int qblk = blk >> 5;          // 0..31
  const int b    = bh >> 4;

  const size_t base = (size_t)bh * S_LEN * DHEAD;
  const float*    Qb = Q + base;
  float* Ob = O + base;

  // per-lane bases for direct L2->reg loads (R15 layouts)
  const _Float16* klane = K2 + base + quad * 128 + x * 8;   // + P*4096 + t*1024 (+512)
  const _Float16* vlane = Vg + base + 256 * quad + 4 * x;   // + P*4096 + t*1024 + m*64
  const float*    mlane = madd_g + b * S_LEN + quad * 4;    // + P*64 + t*16

  const int kvbase = kvh * 16;        // this wave's first 64-kv tile

  // Q fragments (B-operand of S^T = K Q^T) for two q-strips, pre-scaled.
  const int q0 = qblk * 64 + qsub * 32 + x;
  f16x8 qf[2][2];
#pragma unroll
  for (int u = 0; u < 2; ++u) {
    const float* qp = Qb + (size_t)(q0 + u * 16) * DHEAD + quad * 8;
#pragma unroll
    for (int kb = 0; kb < 2; ++kb) {
      float4 a = *(const float4*)(qp + kb * 32);
      float4 c = *(const float4*)(qp + kb * 32 + 4);
      union { f16x2 h[4]; f16x8 v; } r;
      r.h[0] = h2f(pkh(a.x * SCL2E, a.y * SCL2E));
      r.h[1] = h2f(pkh(a.z * SCL2E, a.w * SCL2E));
      r.h[2] = h2f(pkh(c.x * SCL2E, c.y * SCL2E));
      r.h[3] = h2f(pkh(c.z * SCL2E, c.w * SCL2E));
      qf[u][kb] = r.v;
    }
  }

  // register K tiles: double-buffered, named arrays (compile-time selected
  // per unrolled step parity -> no dynamic indexing, no scratch).
  f16x8 kA[4][2], kB[4][2];
  f16x4 vv[4][4];
  f32x4 mi[4];

  auto loadK = [&](int P, f16x8 (&kf)[4][2]) {
#pragma unroll
    for (int t = 0; t < 4; ++t) {
      const _Float16* kp = klane + (size_t)P * 4096 + t * 1024;
      kf[t][0] = *(const f16x8*)(kp);
      kf[t][1] = *(const f16x8*)(kp + 512);
    }
  };

  f32x4 xacc[2][4];
#pragma unroll
  for (int u = 0; u < 2; ++u)
#pragma unroll
    for (int m = 0; m < 4; ++m) xacc[u][m] = (f32x4){0.f, 0.f, 0.f, 0.f};
  float lsum[2] = {0.0f, 0.0f};
  const hf16x2 one2 = {(__fp16)1.0f, (__fp16)1.0f};
  const f32x4 zf = (f32x4){0.f, 0.f, 0.f, 0.f};

  loadK(kvbase, kA);   // prologue: K(tile0) in flight before step 0's QK

  auto step = [&](int p, f16x8 (&kCur)[4][2], f16x8 (&kNxt)[4][2]) {
    const int P = kvbase + p;
    // issue order: mi(P) first (oldest -> its wait leaves younger loads in
    // flight), then K(P+1) prefetch, then V(P).
#pragma unroll
    for (int t = 0; t < 4; ++t)
      mi[t] = *(const f32x4*)(mlane + P * 64 + t * 16);
    if (p + 1 < 16) loadK(P + 1, kNxt);
#pragma unroll
    for (int t = 0; t < 4; ++t)
#pragma unroll
      for (int m = 0; m < 4; ++m)
        vv[t][m] = *(const f16x4*)(vlane + (size_t)P * 4096 + t * 1024 + m * 64);

    // S^T = K Q^T (C=0; mask-bias added on the VALU before exp2)
    f16x4 pf[2][4];
#pragma unroll
    for (int t = 0; t < 4; ++t) {
      const f32x4 miv = mi[t];
#pragma unroll
      for (int u = 0; u < 2; ++u) {
        f32x4 st = __builtin_amdgcn_mfma_f32_16x16x32_f16(kCur[t][0], qf[u][0], zf, 0, 0, 0);
        st = __builtin_amdgcn_mfma_f32_16x16x32_f16(kCur[t][1], qf[u][1], st, 0, 0, 0);
        hf16x2 h0 = pkh(exp2_fast(st.x + miv.x), exp2_fast(st.y + miv.y));
        hf16x2 h1 = pkh(exp2_fast(st.z + miv.z), exp2_fast(st.w + miv.w));
#if __has_builtin(__builtin_amdgcn_fdot2)
        lsum[u] = __builtin_amdgcn_fdot2(h0, one2, lsum[u], false);
        lsum[u] = __builtin_amdgcn_fdot2(h1, one2, lsum[u], false);
#else
        f16x2 a0 = h2f(h0), a1 = h2f(h1);
        lsum[u] += (float)a0.x + (float)a0.y + (float)a1.x + (float)a1.y;
#endif
        union { f16x2 h[2]; f16x4 v; } r;
        r.h[0] = h2f(h0);
        r.h[1] = h2f(h1);
        pf[u][t] = r.v;
      }
    }
    // X^T += V^T P^T (V already in registers; serves both strips)
#pragma unroll
    for (int m = 0; m < 4; ++m) {
      f32x4 x0 = xacc[0][m];
      f32x4 x1 = xacc[1][m];
#pragma unroll
      for (int t = 0; t < 4; ++t) {
        x0 = __builtin_amdgcn_mfma_f32_16x16x16f16(vv[t][m], pf[0][t], x0, 0, 0, 0);
        x1 = __builtin_amdgcn_mfma_f32_16x16x16f16(vv[t][m], pf[1][t], x1, 0, 0, 0);
      }
      xacc[0][m] = x0;
      xacc[1][m] = x1;
    }
  };

  for (int pp = 0; pp < 8; ++pp) {
    step(2 * pp,     kA, kB);
    step(2 * pp + 1, kB, kA);
  }

  // combine kv-halves: kvh=1 waves write partials, kvh=0 waves reduce+store.
  // stride 36 floats keeps f32x4 alignment; one-shot epilogue cost.
  const int soff = (qsub * 64 + lane) * 36;
  if (kvh == 1) {
#pragma unroll
    for (int u = 0; u < 2; ++u) {
#pragma unroll
      for (int m = 0; m < 4; ++m)
        *(f32x4*)(xls + soff + (u * 4 + m) * 4) = xacc[u][m];
      xls[soff + 32 + u] = lsum[u];
    }
  }
  __syncthreads();
  if (kvh == 0) {
#pragma unroll
    for (int u = 0; u < 2; ++u) {
#pragma unroll
      for (int m = 0; m < 4; ++m) {
        f32x4 o = *(const f32x4*)(xls + soff + (u * 4 + m) * 4);
        xacc[u][m].x += o.x; xacc[u][m].y += o.y;
        xacc[u][m].z += o.z; xacc[u][m].w += o.w;
      }
      float l = lsum[u] + xls[soff + 32 + u];
      l += __shfl_xor(l, 16, 64);
      l += __shfl_xor(l, 32, 64);
      const float rl = 1.0f / l;
      float* op = Ob + (size_t)(q0 + u * 16) * DHEAD;
#pragma unroll
      for (int m = 0; m < 4; ++m) {
        float4 o;
        o.x = xacc[u][m].x * rl; o.y = xacc[u][m].y * rl;
        o.z = xacc[u][m].z * rl; o.w = xacc[u][m].w * rl;
        *(float4*)(op + m * 16 + quad * 4) = o;
      }
    }
  }
}

extern "C" void kernel_launch(void* const* d_in, const int* in_sizes, int n_in,
                              void* d_out, int out_size, void* d_ws, size_t ws_size,
                              hipStream_t stream) {
  const float* Q = (const float*)d_in[0];
  const float* K = (const float*)d_in[1];
  const float* V = (const float*)d_in[2];
  const float* M = (const float*)d_in[3];
  float* O = (float*)d_out;

  _Float16* K2   = (_Float16*)d_ws;
  _Float16* Vg   = K2 + 4194304;                         // +8 MB
  float*    madd = (float*)((char*)d_ws + 16777216);     // +16 MB
  hipLaunchKernelGGL(prep, dim3(6144), dim3(256), 0, stream, K, V, M, K2, Vg, madd);
  hipLaunchKernelGGL(attn_ws, dim3(1024), dim3(256), 0, stream, Q, K2, Vg, madd, O);
}

// Round 13
// 154.099 us; speedup vs baseline: 1.4733x; 1.4733x over previous
//
#include <hip/hip_runtime.h>
#include <hip/hip_fp16.h>
#include <stdint.h>

// SoftmaxSelfAttention: B=2 H=16 S=2048 D=64, fp32 in/out.
// R17 = R16 with ONE token changed: __launch_bounds__(256,4) -> (256,2).
// R16 post-mortem: the drift@4waves/SIMD experiment never ran — allocator
// gave VGPR=64 (body needs ~96-110) and spilled the register K/V tiles:
// WRITE_SIZE 285MB / FETCH 132MB of scratch traffic, 148us. Toolchain rule
// (5 data points): only min-waves-hint=2 yields a sane allocation (R6:88,
// R14:88, R15:96); (256,4), (512,*), waves_per_eu(4,4) all collapse to <=64.
// With (256,2): cap 256, natural allocation ~96-110 <= 128 -> HW occupancy
// 4 waves/SIMD via 4 blocks/CU of 4 waves (LDS 18.4KB x4 = 74KB ok).
// Structure unchanged from R16: grid 1024 (32 qblocks of 64 rows x 32 bh),
// 4 free-drifting waves = qsub(2) x kvhalf(2), each sweeps 16 of 32
// kv-tiles; K dbuf in regs, V+mi direct from L2 (R15 layouts); no barriers
// in the loop; one __syncthreads for the kv-half combine epilogue.

#define S_LEN   2048
#define DHEAD   64
#define CEXP    9.0f
#define SCL2E   0.18033688011112042f    // (1/sqrt(64)) * log2(e)
#define L2E     1.4426950408889634f

typedef __attribute__((ext_vector_type(4))) float    f32x4;
typedef __attribute__((ext_vector_type(2))) _Float16 f16x2;
typedef __attribute__((ext_vector_type(4))) _Float16 f16x4;
typedef __attribute__((ext_vector_type(8))) _Float16 f16x8;
typedef __attribute__((ext_vector_type(2))) __fp16   hf16x2;

static __device__ __forceinline__ float exp2_fast(float x) {
#if __has_builtin(__builtin_amdgcn_exp2f)
  return __builtin_amdgcn_exp2f(x);
#else
  float r;
  asm("v_exp_f32 %0, %1" : "=v"(r) : "v"(x));
  return r;
#endif
}

static __device__ __forceinline__ hf16x2 pkh(float a, float b) {
  return __builtin_amdgcn_cvt_pkrtz(a, b);
}
static __device__ __forceinline__ f16x2 h2f(hf16x2 h) {
  union { hf16x2 i; f16x2 o; } u; u.i = h; return u.o;
}

// ---------------------------------------------------------------- prep ----
// (unchanged from R15/R16, verified)
// Blocks [0,2048): K image, CHUNK-MAJOR for direct-reg fragment loads:
// dst granule idx = bh<<14 | p<<9 | t<<7 | c<<4 | x holds
// K[bh][kv = p*64+t*16+x][d = c*8 .. +8] as 8 f16. Also madd_g[b][kv].
// Blocks [2048,6144): V image, granule-major:
// granule (bh,j,g,d) = {V[64j+4g+i][d], i=0..3} at flat (bh<<15|j<<10|g<<6|d).
__global__ __launch_bounds__(256) void prep(
    const float* __restrict__ K, const float* __restrict__ V,
    const float* __restrict__ Mk, _Float16* __restrict__ K2,
    _Float16* __restrict__ Vg, float* __restrict__ madd_g) {
  const int gb = blockIdx.x;
  if (gb < 2048) {
    const int idx = gb * 256 + threadIdx.x;   // bh<<14 | p<<9 | t<<7 | c<<4 | x
    const int x  = idx & 15;
    const int c  = (idx >> 4) & 7;
    const int t  = (idx >> 7) & 3;
    const int p  = (idx >> 9) & 31;
    const int bh = idx >> 14;
    const int kv = p * 64 + t * 16 + x;
    const float* src = K + ((size_t)bh * S_LEN + kv) * DHEAD + c * 8;
    float4 a = *(const float4*)(src);
    float4 d = *(const float4*)(src + 4);
    union { f16x2 h[4]; f16x8 v; } r;
    r.h[0] = h2f(pkh(a.x, a.y)); r.h[1] = h2f(pkh(a.z, a.w));
    r.h[2] = h2f(pkh(d.x, d.y)); r.h[3] = h2f(pkh(d.z, d.w));
    *(f16x8*)(K2 + (size_t)idx * 8) = r.v;
    if (idx < 2 * S_LEN)
      madd_g[idx] = -CEXP - (1.0e6f * L2E) * (1.0f - Mk[idx]);
  } else {
    const int idx = (gb - 2048) * 256 + threadIdx.x;  // bh<<15 | j<<10 | g<<6 | d
    const int d  = idx & 63;
    const int g  = (idx >> 6) & 15;
    const int j  = (idx >> 10) & 31;
    const int bh = idx >> 15;
    const float* src = V + ((size_t)bh * S_LEN + j * 64 + g * 4) * DHEAD + d;
    float v0 = src[0], v1 = src[64], v2 = src[128], v3 = src[192];
    union { f16x2 h[2]; f16x4 v; } r;
    r.h[0] = h2f(pkh(v0, v1)); r.h[1] = h2f(pkh(v2, v3));
    *(f16x4*)(Vg + (size_t)idx * 4) = r.v;
  }
}

// ---------------------------------------------------------------- main ----
// 256 threads = 4 free-drifting waves: wave = qsub | kvh<<1.
// Wave (qsub,kvh): q-strips qblk*64 + qsub*32 + {0,16}, kv half kvh.
// No LDS/barriers in the loop; K dbuf in regs, V+mi direct from L2.
// One __syncthreads for the kv-half combine epilogue.
__global__ __launch_bounds__(256, 2) void attn_ws(
    const float* __restrict__ Q, const _Float16* __restrict__ K2,
    const _Float16* __restrict__ Vg, const float* __restrict__ madd_g,
    float* __restrict__ O) {
  __shared__ __align__(16) float xls[4608];   // 18.4KB combine scratch

  const int tid  = threadIdx.x;       // 0..255
  const int lane = tid & 63;
  const int wave = tid >> 6;          // 0..3
  const int qsub = wave & 1;
  const int kvh  = wave >> 1;
  const int quad = lane >> 4;
  const int x    = lane & 15;

  // grid 1024: 32 q-blocks (64 rows) x 32 bh; same-bh blocks share an XCD.
  const int blk  = blockIdx.x;
  const int bh   = (blk & 7) | (((blk >> 3) & 3) << 3);
  const int qblk = blk >> 5;          // 0..31
  const int b    = bh >> 4;

  const size_t base = (size_t)bh * S_LEN * DHEAD;
  const float*    Qb = Q + base;
  float* Ob = O + base;

  // per-lane bases for direct L2->reg loads (R15 layouts)
  const _Float16* klane = K2 + base + quad * 128 + x * 8;   // + P*4096 + t*1024 (+512)
  const _Float16* vlane = Vg + base + 256 * quad + 4 * x;   // + P*4096 + t*1024 + m*64
  const float*    mlane = madd_g + b * S_LEN + quad * 4;    // + P*64 + t*16

  const int kvbase = kvh * 16;        // this wave's first 64-kv tile

  // Q fragments (B-operand of S^T = K Q^T) for two q-strips, pre-scaled.
  const int q0 = qblk * 64 + qsub * 32 + x;
  f16x8 qf[2][2];
#pragma unroll
  for (int u = 0; u < 2; ++u) {
    const float* qp = Qb + (size_t)(q0 + u * 16) * DHEAD + quad * 8;
#pragma unroll
    for (int kb = 0; kb < 2; ++kb) {
      float4 a = *(const float4*)(qp + kb * 32);
      float4 c = *(const float4*)(qp + kb * 32 + 4);
      union { f16x2 h[4]; f16x8 v; } r;
      r.h[0] = h2f(pkh(a.x * SCL2E, a.y * SCL2E));
      r.h[1] = h2f(pkh(a.z * SCL2E, a.w * SCL2E));
      r.h[2] = h2f(pkh(c.x * SCL2E, c.y * SCL2E));
      r.h[3] = h2f(pkh(c.z * SCL2E, c.w * SCL2E));
      qf[u][kb] = r.v;
    }
  }

  // register K tiles: double-buffered, named arrays (compile-time selected
  // per unrolled step parity -> no dynamic indexing, no scratch).
  f16x8 kA[4][2], kB[4][2];
  f16x4 vv[4][4];
  f32x4 mi[4];

  auto loadK = [&](int P, f16x8 (&kf)[4][2]) {
#pragma unroll
    for (int t = 0; t < 4; ++t) {
      const _Float16* kp = klane + (size_t)P * 4096 + t * 1024;
      kf[t][0] = *(const f16x8*)(kp);
      kf[t][1] = *(const f16x8*)(kp + 512);
    }
  };

  f32x4 xacc[2][4];
#pragma unroll
  for (int u = 0; u < 2; ++u)
#pragma unroll
    for (int m = 0; m < 4; ++m) xacc[u][m] = (f32x4){0.f, 0.f, 0.f, 0.f};
  float lsum[2] = {0.0f, 0.0f};
  const hf16x2 one2 = {(__fp16)1.0f, (__fp16)1.0f};
  const f32x4 zf = (f32x4){0.f, 0.f, 0.f, 0.f};

  loadK(kvbase, kA);   // prologue: K(tile0) in flight before step 0's QK

  auto step = [&](int p, f16x8 (&kCur)[4][2], f16x8 (&kNxt)[4][2]) {
    const int P = kvbase + p;
    // issue order: mi(P) first (oldest -> its wait leaves younger loads in
    // flight), then K(P+1) prefetch, then V(P).
#pragma unroll
    for (int t = 0; t < 4; ++t)
      mi[t] = *(const f32x4*)(mlane + P * 64 + t * 16);
    if (p + 1 < 16) loadK(P + 1, kNxt);
#pragma unroll
    for (int t = 0; t < 4; ++t)
#pragma unroll
      for (int m = 0; m < 4; ++m)
        vv[t][m] = *(const f16x4*)(vlane + (size_t)P * 4096 + t * 1024 + m * 64);

    // S^T = K Q^T (C=0; mask-bias added on the VALU before exp2)
    f16x4 pf[2][4];
#pragma unroll
    for (int t = 0; t < 4; ++t) {
      const f32x4 miv = mi[t];
#pragma unroll
      for (int u = 0; u < 2; ++u) {
        f32x4 st = __builtin_amdgcn_mfma_f32_16x16x32_f16(kCur[t][0], qf[u][0], zf, 0, 0, 0);
        st = __builtin_amdgcn_mfma_f32_16x16x32_f16(kCur[t][1], qf[u][1], st, 0, 0, 0);
        hf16x2 h0 = pkh(exp2_fast(st.x + miv.x), exp2_fast(st.y + miv.y));
        hf16x2 h1 = pkh(exp2_fast(st.z + miv.z), exp2_fast(st.w + miv.w));
#if __has_builtin(__builtin_amdgcn_fdot2)
        lsum[u] = __builtin_amdgcn_fdot2(h0, one2, lsum[u], false);
        lsum[u] = __builtin_amdgcn_fdot2(h1, one2, lsum[u], false);
#else
        f16x2 a0 = h2f(h0), a1 = h2f(h1);
        lsum[u] += (float)a0.x + (float)a0.y + (float)a1.x + (float)a1.y;
#endif
        union { f16x2 h[2]; f16x4 v; } r;
        r.h[0] = h2f(h0);
        r.h[1] = h2f(h1);
        pf[u][t] = r.v;
      }
    }
    // X^T += V^T P^T (V already in registers; serves both strips)
#pragma unroll
    for (int m = 0; m < 4; ++m) {
      f32x4 x0 = xacc[0][m];
      f32x4 x1 = xacc[1][m];
#pragma unroll
      for (int t = 0; t < 4; ++t) {
        x0 = __builtin_amdgcn_mfma_f32_16x16x16f16(vv[t][m], pf[0][t], x0, 0, 0, 0);
        x1 = __builtin_amdgcn_mfma_f32_16x16x16f16(vv[t][m], pf[1][t], x1, 0, 0, 0);
      }
      xacc[0][m] = x0;
      xacc[1][m] = x1;
    }
  };

  for (int pp = 0; pp < 8; ++pp) {
    step(2 * pp,     kA, kB);
    step(2 * pp + 1, kB, kA);
  }

  // combine kv-halves: kvh=1 waves write partials, kvh=0 waves reduce+store.
  // stride 36 floats keeps f32x4 alignment; one-shot epilogue cost.
  const int soff = (qsub * 64 + lane) * 36;
  if (kvh == 1) {
#pragma unroll
    for (int u = 0; u < 2; ++u) {
#pragma unroll
      for (int m = 0; m < 4; ++m)
        *(f32x4*)(xls + soff + (u * 4 + m) * 4) = xacc[u][m];
      xls[soff + 32 + u] = lsum[u];
    }
  }
  __syncthreads();
  if (kvh == 0) {
#pragma unroll
    for (int u = 0; u < 2; ++u) {
#pragma unroll
      for (int m = 0; m < 4; ++m) {
        f32x4 o = *(const f32x4*)(xls + soff + (u * 4 + m) * 4);
        xacc[u][m].x += o.x; xacc[u][m].y += o.y;
        xacc[u][m].z += o.z; xacc[u][m].w += o.w;
      }
      float l = lsum[u] + xls[soff + 32 + u];
      l += __shfl_xor(l, 16, 64);
      l += __shfl_xor(l, 32, 64);
      const float rl = 1.0f / l;
      float* op = Ob + (size_t)(q0 + u * 16) * DHEAD;
#pragma unroll
      for (int m = 0; m < 4; ++m) {
        float4 o;
        o.x = xacc[u][m].x * rl; o.y = xacc[u][m].y * rl;
        o.z = xacc[u][m].z * rl; o.w = xacc[u][m].w * rl;
        *(float4*)(op + m * 16 + quad * 4) = o;
      }
    }
  }
}

extern "C" void kernel_launch(void* const* d_in, const int* in_sizes, int n_in,
                              void* d_out, int out_size, void* d_ws, size_t ws_size,
                              hipStream_t stream) {
  const float* Q = (const float*)d_in[0];
  const float* K = (const float*)d_in[1];
  const float* V = (const float*)d_in[2];
  const float* M = (const float*)d_in[3];
  float* O = (float*)d_out;

  _Float16* K2   = (_Float16*)d_ws;
  _Float16* Vg   = K2 + 4194304;                         // +8 MB
  float*    madd = (float*)((char*)d_ws + 16777216);     // +16 MB
  hipLaunchKernelGGL(prep, dim3(6144), dim3(256), 0, stream, K, V, M, K2, Vg, madd);
  hipLaunchKernelGGL(attn_ws, dim3(1024), dim3(256), 0, stream, Q, K2, Vg, madd, O);
}

// Round 15
// 150.115 us; speedup vs baseline: 1.5124x; 1.0265x over previous
//
#include <hip/hip_runtime.h>
#include <hip/hip_fp16.h>
#include <stdint.h>

// SoftmaxSelfAttention: B=2 H=16 S=2048 D=64, fp32 in/out.
// R19: cross-step ILP on R14's VERIFIED staging skeleton. R18 (depth-2,
// 3-buffer, interleave — three sync variables at once) NaN'd and the race
// resists analysis; retreat to R14's 2-buffer depth-1 discipline (passed 7x:
// stage(p+1) overwrites the buffer read one barrier ago) and change ONLY
// the compute order: per iter VLOAD(p-1) -> stage(p+1) -> [QK_t(p) ⊗
// PV_m(p-1)]x4 -> barrier. pfA/pfB alternate by parity (static names);
// buffer index passed as literal per call site. V consumption is one step
// behind its load -> V L2 latency hides under a full QK phase. Hypothesis
// under test: R11's 57us = MFMA 17 + VALU 19 + LDS 25 run sequentially;
// interleaving QK(p) with PV(p-1) overlaps the pipes within a wave.

#define S_LEN   2048
#define DHEAD   64
#define CEXP    9.0f
#define SCL2E   0.18033688011112042f    // (1/sqrt(64)) * log2(e)
#define L2E     1.4426950408889634f

typedef __attribute__((ext_vector_type(4))) float    f32x4;
typedef __attribute__((ext_vector_type(2))) _Float16 f16x2;
typedef __attribute__((ext_vector_type(4))) _Float16 f16x4;
typedef __attribute__((ext_vector_type(8))) _Float16 f16x8;
typedef __attribute__((ext_vector_type(2))) __fp16   hf16x2;

static __device__ __forceinline__ float exp2_fast(float x) {
#if __has_builtin(__builtin_amdgcn_exp2f)
  return __builtin_amdgcn_exp2f(x);
#else
  float r;
  asm("v_exp_f32 %0, %1" : "=v"(r) : "v"(x));
  return r;
#endif
}

static __device__ __forceinline__ hf16x2 pkh(float a, float b) {
  return __builtin_amdgcn_cvt_pkrtz(a, b);
}
static __device__ __forceinline__ f16x2 h2f(hf16x2 h) {
  union { hf16x2 i; f16x2 o; } u; u.i = h; return u.o;
}

static __device__ __forceinline__ float sum2(float acc, hf16x2 h0, hf16x2 h1) {
#if __has_builtin(__builtin_amdgcn_fdot2)
  const hf16x2 one2 = {(__fp16)1.0f, (__fp16)1.0f};
  acc = __builtin_amdgcn_fdot2(h0, one2, acc, false);
  acc = __builtin_amdgcn_fdot2(h1, one2, acc, false);
  return acc;
#else
  f16x2 a0 = h2f(h0), a1 = h2f(h1);
  return acc + (float)a0.x + (float)a0.y + (float)a1.x + (float)a1.y;
#endif
}

#define GLDS16(g, l)                                                  \
  __builtin_amdgcn_global_load_lds(                                   \
      (const __attribute__((address_space(1))) void*)(g),             \
      (__attribute__((address_space(3))) void*)(l), 16, 0, 0)

// ---------------------------------------------------------------- prep ----
// (R14 verbatim, verified)
// Blocks [0,2048): K image, chunk c (8 f16) of row kv at rotated pos
// (c+kv)&7; also madd_g[b][kv]. Blocks [2048,6144): V image, granule-major:
// granule (bh,j,g,d) = {V[64j+4g+i][d], i=0..3} at flat (bh<<15|j<<10|g<<6|d).
__global__ __launch_bounds__(256) void prep(
    const float* __restrict__ K, const float* __restrict__ V,
    const float* __restrict__ Mk, _Float16* __restrict__ Kswz,
    _Float16* __restrict__ Vg, float* __restrict__ madd_g) {
  const int gb = blockIdx.x;
  if (gb < 2048) {
    const int idx = gb * 256 + threadIdx.x;   // bh<<14 | kv<<3 | c
    const int c  = idx & 7;
    const int kv = (idx >> 3) & 2047;
    const int bh = idx >> 14;
    const float* src = K + ((size_t)bh * S_LEN + kv) * DHEAD + c * 8;
    float4 a = *(const float4*)(src);
    float4 d = *(const float4*)(src + 4);
    union { f16x2 h[4]; f16x8 v; } r;
    r.h[0] = h2f(pkh(a.x, a.y)); r.h[1] = h2f(pkh(a.z, a.w));
    r.h[2] = h2f(pkh(d.x, d.y)); r.h[3] = h2f(pkh(d.z, d.w));
    *(f16x8*)(Kswz + ((size_t)bh * S_LEN + kv) * DHEAD + ((c + kv) & 7) * 8) = r.v;
    if (idx < 2 * S_LEN)
      madd_g[idx] = -CEXP - (1.0e6f * L2E) * (1.0f - Mk[idx]);
  } else {
    const int idx = (gb - 2048) * 256 + threadIdx.x;  // bh<<15 | j<<10 | g<<6 | d
    const int d  = idx & 63;
    const int g  = (idx >> 6) & 15;
    const int j  = (idx >> 10) & 31;
    const int bh = idx >> 15;
    const float* src = V + ((size_t)bh * S_LEN + j * 64 + g * 4) * DHEAD + d;
    float v0 = src[0], v1 = src[64], v2 = src[128], v3 = src[192];
    union { f16x2 h[2]; f16x4 v; } r;
    r.h[0] = h2f(pkh(v0, v1)); r.h[1] = h2f(pkh(v2, v3));
    *(f16x4*)(Vg + (size_t)idx * 4) = r.v;
  }
}

// ----- per-chunk macros (literal bi/t/m -> no dynamic register indexing) --
#define QK_T(bi, t, pf)                                                       \
  {                                                                           \
    f16x8 ka0 = *(const f16x8*)(k0base + (bi) * 4096 + (t) * 1024);           \
    f16x8 ka1 = *(const f16x8*)(k1base + (bi) * 4096 + (t) * 1024);           \
    f32x4 mi  = *(const f32x4*)(mpbase + (bi) * 64 + (t) * 16);               \
    _Pragma("unroll")                                                         \
    for (int u = 0; u < 2; ++u) {                                             \
      f32x4 st = __builtin_amdgcn_mfma_f32_16x16x32_f16(ka0, qf[u][0], mi, 0, 0, 0); \
      st = __builtin_amdgcn_mfma_f32_16x16x32_f16(ka1, qf[u][1], st, 0, 0, 0);       \
      hf16x2 h0 = pkh(exp2_fast(st.x), exp2_fast(st.y));                      \
      hf16x2 h1 = pkh(exp2_fast(st.z), exp2_fast(st.w));                      \
      lsum[u] = sum2(lsum[u], h0, h1);                                        \
      union { f16x2 h[2]; f16x4 v; } r;                                       \
      r.h[0] = h2f(h0);                                                       \
      r.h[1] = h2f(h1);                                                       \
      pf[u][t] = r.v;                                                         \
    }                                                                         \
  }

#define PV_M(m, pf)                                                           \
  {                                                                           \
    f32x4 x0 = xacc[0][m];                                                    \
    f32x4 x1 = xacc[1][m];                                                    \
    _Pragma("unroll")                                                         \
    for (int t = 0; t < 4; ++t) {                                             \
      x0 = __builtin_amdgcn_mfma_f32_16x16x16f16(vv[t][m], pf[0][t], x0, 0, 0, 0); \
      x1 = __builtin_amdgcn_mfma_f32_16x16x16f16(vv[t][m], pf[1][t], x1, 0, 0, 0); \
    }                                                                         \
    xacc[0][m] = x0;                                                          \
    xacc[1][m] = x1;                                                          \
  }

#define VLOAD(p)                                                              \
  _Pragma("unroll")                                                           \
  for (int t = 0; t < 4; ++t)                                                 \
    _Pragma("unroll")                                                         \
    for (int m = 0; m < 4; ++m)                                               \
      vv[t][m] = *(const f16x4*)(vlane + (size_t)(p) * 4096 + t * 1024 + m * 64);

// pipelined iteration i (i>=1): V(i-1) -> stage(i+1) -> QK(i, buf bi)->pfN
// interleaved with PV(i-1, pfO) -> barrier. Staging discipline = R14:
// stage(i+1) overwrites the buffer of tile i-1, read one barrier ago.
#define PITER(i, bi, pfN, pfO)                                                \
  {                                                                           \
    VLOAD((i) - 1);                                                           \
    __builtin_amdgcn_sched_barrier(0);                                        \
    if ((i) < 31) stage((i) + 1, ((i) + 1) & 1);                              \
    QK_T(bi, 0, pfN); PV_M(0, pfO);                                           \
    QK_T(bi, 1, pfN); PV_M(1, pfO);                                           \
    QK_T(bi, 2, pfN); PV_M(2, pfO);                                           \
    QK_T(bi, 3, pfN); PV_M(3, pfO);                                           \
    __syncthreads();                                                          \
  }

// ---------------------------------------------------------------- main ----
// 256 threads = 4 waves; each wave owns 2 q-strips (wave*16 and +64) of a
// 128-row q-block. Full kv sweep, 32 tiles of 64 kv. K+m double-buffered in
// LDS exactly as R14; V register-resident, loaded one step before use.
__global__ __launch_bounds__(256, 2) void attn_ws(
    const float* __restrict__ Q, const _Float16* __restrict__ Kswz,
    const _Float16* __restrict__ Vg, const float* __restrict__ madd_g,
    float* __restrict__ O) {
  __shared__ __align__(16) _Float16 smem[8448];   // 2x4096 K + 2x64 f32 m

  const int tid  = threadIdx.x;       // 0..255
  const int lane = tid & 63;
  const int wave = tid >> 6;          // 0..3
  const int quad = lane >> 4;
  const int x    = lane & 15;

  // grid 512: 16 q-blocks (128 rows) x 32 bh; same-bh blocks share an XCD.
  const int blk  = blockIdx.x;
  const int bh   = (blk & 7) | (((blk >> 3) & 3) << 3);
  const int qblk = blk >> 5;          // 0..15
  const int b    = bh >> 4;

  const size_t base = (size_t)bh * S_LEN * DHEAD;
  const float*    Qb = Q + base;
  const _Float16* Kb = Kswz + base;
  const _Float16* Vb = Vg + base;
  const float*    Mb = madd_g + b * S_LEN;
  float* Ob = O + base;

  float* const mbase = (float*)(smem + 8192);      // 2 bufs x 64 floats

  // Q fragments (B-operand of S^T = K Q^T) for two q-strips, pre-scaled.
  const int q0 = qblk * 128 + wave * 16 + x;
  f16x8 qf[2][2];
#pragma unroll
  for (int u = 0; u < 2; ++u) {
    const float* qp = Qb + (size_t)(q0 + u * 64) * DHEAD + quad * 8;
#pragma unroll
    for (int kb = 0; kb < 2; ++kb) {
      float4 a = *(const float4*)(qp + kb * 32);
      float4 c = *(const float4*)(qp + kb * 32 + 4);
      union { f16x2 h[4]; f16x8 v; } r;
      r.h[0] = h2f(pkh(a.x * SCL2E, a.y * SCL2E));
      r.h[1] = h2f(pkh(a.z * SCL2E, a.w * SCL2E));
      r.h[2] = h2f(pkh(c.x * SCL2E, c.y * SCL2E));
      r.h[3] = h2f(pkh(c.z * SCL2E, c.w * SCL2E));
      qf[u][kb] = r.v;
    }
  }

  // stage one 64-kv K tile (8KB) + m (256B) into buffer bi (R14 verbatim).
  auto stage = [&](int p, int bi) {
    const _Float16* ks = Kb + (size_t)p * 4096 + tid * 8;
    _Float16* kd = smem + bi * 4096 + tid * 8;
    GLDS16(ks,        kd);
    GLDS16(ks + 2048, kd + 2048);
    if (tid < 16)
      GLDS16(Mb + p * 64 + tid * 4, mbase + bi * 64 + tid * 4);
  };

  // per-lane bases
  const _Float16* vlane  = Vb + 256 * quad + 4 * x;
  const _Float16* k0base = smem + x * 64 + ((quad + x) & 7) * 8;
  const _Float16* k1base = smem + x * 64 + ((quad + 4 + x) & 7) * 8;
  const float*    mpbase = mbase + quad * 4;

  f32x4 xacc[2][4];
#pragma unroll
  for (int u = 0; u < 2; ++u)
#pragma unroll
    for (int m = 0; m < 4; ++m) xacc[u][m] = (f32x4){0.f, 0.f, 0.f, 0.f};
  float lsum[2] = {0.0f, 0.0f};

  f16x4 pfA[2][4], pfB[2][4];
  f16x4 vv[4][4];

  // prologue: tile 0 staged+drained; iter 0 = stage(1) + QK(0)->pfA (no PV).
  stage(0, 0);
  __syncthreads();
  stage(1, 1);
  QK_T(0, 0, pfA); QK_T(0, 1, pfA); QK_T(0, 2, pfA); QK_T(0, 3, pfA);
  __syncthreads();

  // steady state: i = 1..30 in parity pairs, then i = 31 (no stage).
#pragma unroll 1
  for (int ii = 0; ii < 15; ++ii) {
    const int i = 2 * ii + 1;
    PITER(i,     1, pfB, pfA);   // QK(odd)->pfB, PV(even)<-pfA
    PITER(i + 1, 0, pfA, pfB);   // QK(even)->pfA, PV(odd)<-pfB
  }
  PITER(31, 1, pfB, pfA);        // QK(31)->pfB, PV(30)<-pfA
  // tail: PV(31) only.
  VLOAD(31);
  PV_M(0, pfB); PV_M(1, pfB); PV_M(2, pfB); PV_M(3, pfB);

  // epilogue: reduce l across quads (same q = x), normalize, store.
#pragma unroll
  for (int u = 0; u < 2; ++u) {
    float l = lsum[u];
    l += __shfl_xor(l, 16, 64);
    l += __shfl_xor(l, 32, 64);
    const float rl = 1.0f / l;
    float* op = Ob + (size_t)(q0 + u * 64) * DHEAD;
#pragma unroll
    for (int m = 0; m < 4; ++m) {
      float4 o;
      o.x = xacc[u][m].x * rl; o.y = xacc[u][m].y * rl;
      o.z = xacc[u][m].z * rl; o.w = xacc[u][m].w * rl;
      *(float4*)(op + m * 16 + quad * 4) = o;
    }
  }
}

extern "C" void kernel_launch(void* const* d_in, const int* in_sizes, int n_in,
                              void* d_out, int out_size, void* d_ws, size_t ws_size,
                              hipStream_t stream) {
  const float* Q = (const float*)d_in[0];
  const float* K = (const float*)d_in[1];
  const float* V = (const float*)d_in[2];
  const float* M = (const float*)d_in[3];
  float* O = (float*)d_out;

  _Float16* Kswz = (_Float16*)d_ws;
  _Float16* Vg   = Kswz + 4194304;                       // +8 MB
  float*    madd = (float*)((char*)d_ws + 16777216);     // +16 MB
  hipLaunchKernelGGL(prep, dim3(6144), dim3(256), 0, stream, K, V, M, Kswz, Vg, madd);
  hipLaunchKernelGGL(attn_ws, dim3(512), dim3(256), 0, stream, Q, Kswz, Vg, madd, O);
}